// Round 3
// baseline (439.524 us; speedup 1.0000x reference)
//
#include <hip/hip_runtime.h>

#define NN 20000      // nodes
#define NE 320000     // edges
#define BB 16         // batch
#define PP 12         // periods
#define NCOL 384      // BB*PP*2 feature columns
#define OUT_OFF (BB*PP*NN)
#define SLICES 8
#define SCOLS 48      // 384/8 ; slice footprint 20000*48*4B = 3.84 MB <= 4 MB L2/XCD

// ---------------- small helpers ----------------
__device__ __forceinline__ float sigmoidf_(float v) {
    return __fdividef(1.f, 1.f + __expf(-v));
}
__device__ __forceinline__ float tanh_fast(float v) {
    v = fminf(fmaxf(v, -15.f), 15.f);
    float e = __expf(-2.f * v);
    return __fdividef(1.f - e, 1.f + e);
}

// ---------------- K1: init deg (self-loop weight 1) and counts ----------------
__global__ __launch_bounds__(256) void init_kernel(float* deg, int* cnt) {
    int i = blockIdx.x * 256 + threadIdx.x;
    if (i < NN) { deg[i] = 1.0f; cnt[i] = 0; }
}

// ---------------- K2: degree + per-dst edge count ----------------
__global__ __launch_bounds__(256) void degcnt_kernel(const int* __restrict__ ei,
                                                     const float* __restrict__ ew,
                                                     float* deg, int* cnt) {
    int e = blockIdx.x * 256 + threadIdx.x;
    if (e < NE) {
        int d = ei[NE + e];               // dst row of edge_index
        atomicAdd(&deg[d], ew[e]);
        atomicAdd(&cnt[d], 1);
    }
}

// ---------------- K3: fast single-pass scan (20 elems/thread) + dinv fused ----------------
__global__ __launch_bounds__(1024) void scan_kernel(const int* __restrict__ cnt,
                                                    const float* __restrict__ deg,
                                                    int* __restrict__ rowp,
                                                    int* __restrict__ cur,
                                                    float* __restrict__ dinv) {
    __shared__ int lds[1024];
    int tid = threadIdx.x;
    int base = tid * 20;                  // 1024*20 = 20480 >= NN
    int local[20];
    int s = 0;
    #pragma unroll
    for (int k = 0; k < 20; ++k) {
        int i = base + k;
        int v = (i < NN) ? cnt[i] : 0;
        local[k] = s;
        s += v;
    }
    lds[tid] = s;
    __syncthreads();
    for (int off = 1; off < 1024; off <<= 1) {
        int add = (tid >= off) ? lds[tid - off] : 0;
        __syncthreads();
        lds[tid] += add;
        __syncthreads();
    }
    int pre = (tid > 0) ? lds[tid - 1] : 0;
    #pragma unroll
    for (int k = 0; k < 20; ++k) {
        int i = base + k;
        if (i < NN) {
            int ex = pre + local[k];
            rowp[i] = ex; cur[i] = ex;
            float dg = deg[i];
            dinv[i] = dg > 0.f ? 1.0f / sqrtf(dg) : 0.f;
        }
    }
    if (tid == 0) rowp[NN] = lds[1023];   // == NE
}

// ---------------- K4: scatter edges into CSR as packed {col, normval} int2 ----------------
__global__ __launch_bounds__(256) void scatter_kernel(const int* __restrict__ ei,
                                                      const float* __restrict__ ew,
                                                      const float* __restrict__ dinv,
                                                      int* cur, int2* __restrict__ epk) {
    int e = blockIdx.x * 256 + threadIdx.x;
    if (e < NE) {
        int s = ei[e];
        int d = ei[NE + e];
        int pos = atomicAdd(&cur[d], 1);
        float v = dinv[s] * ew[e] * dinv[d];
        epk[pos] = make_int2(s, __float_as_int(v));
    }
}

// ---------------- K5: fold tiny matrices + softmax into const block ----------------
// layout: Az0[0:12] Az1[12:24] cz[24:36] Ah0[36:48] Ah1[48:60] ch[60:72]
//         probs[72:84] W1[84:228] b1[228:240] W2[240:384] b2[384:396]
__global__ __launch_bounds__(256) void prep_kernel(const float* __restrict__ Wz, const float* __restrict__ bz,
                                                   const float* __restrict__ Wh, const float* __restrict__ bh,
                                                   const float* __restrict__ Lzw, const float* __restrict__ Lzb,
                                                   const float* __restrict__ Lhw, const float* __restrict__ Lhb,
                                                   const float* __restrict__ att,
                                                   const float* __restrict__ W1, const float* __restrict__ b1,
                                                   const float* __restrict__ W2, const float* __restrict__ b2,
                                                   float* __restrict__ cst) {
    int t = threadIdx.x;
    if (t < PP) {
        int p = t;
        float az0 = 0.f, az1 = 0.f, cz = 0.f, ah0 = 0.f, ah1 = 0.f, ch = 0.f;
        for (int q = 0; q < PP; ++q) {
            float lz = Lzw[q * PP + p], lh = Lhw[q * PP + p];
            az0 += Wz[q] * lz;
            az1 += Wz[PP + q] * lz;
            cz  += bz[q] * lz;
            ah0 += Wh[q] * lh;
            ah1 += Wh[PP + q] * lh;
            ch  += bh[q] * lh;
        }
        cz += Lzb[p]; ch += Lhb[p];
        cst[p] = az0; cst[12 + p] = az1; cst[24 + p] = cz;
        cst[36 + p] = ah0; cst[48 + p] = ah1; cst[60 + p] = ch;
        float m = att[0];
        for (int q = 1; q < PP; ++q) m = fmaxf(m, att[q]);
        float ssum = 0.f;
        for (int q = 0; q < PP; ++q) ssum += __expf(att[q] - m);
        cst[72 + p] = __expf(att[p] - m) / ssum;
    }
    if (t < 144) { cst[84 + t] = W1[t]; cst[240 + t] = W2[t]; }
    if (t < PP) { cst[228 + t] = b1[t]; cst[384 + t] = b2[t]; }
}

// ---------------- K6: build X[N][384] (transposed, GAIN-filled) via LDS tiles ----------------
#define TILE 32
__global__ __launch_bounds__(256) void buildx_kernel(const float* __restrict__ x,
                                                     const float* __restrict__ mask,
                                                     const float* __restrict__ noise,
                                                     float* __restrict__ X) {
    __shared__ float tile[TILE][NCOL + 1];   // stride 385 -> conflict-free
    int tid = threadIdx.x;
    int n0 = blockIdx.x * TILE;
    int i = tid & 31;
    int prb = tid >> 5;
    #pragma unroll 4
    for (int it = 0; it < 24; ++it) {
        int pr = it * 8 + prb;                   // pr = b*12 + t
        int g = pr * NN + n0 + i;
        float m = mask[g];
        float xv = x[g];
        float nz = noise[g];
        float xf = m * xv + (1.f - m) * nz;
        int col = pr * 2;
        tile[i][col]     = xf;
        tile[i][col + 1] = m;
    }
    __syncthreads();
    #pragma unroll 4
    for (int it = 0; it < 48; ++it) {
        int idx = it * 256 + tid;
        int r = idx / NCOL;
        int c = idx - r * NCOL;
        X[(n0 + r) * NCOL + c] = tile[r][c];
    }
}

// ---------------- K7: XCD-partitioned gather SpMM with edge lookahead ----------------
// slice = blockIdx & 7 -> each XCD's gathers confined to a 3.84 MB L2-resident X slice.
// Edge records read with wave-uniform index (scalar path) + 8-deep register lookahead
// so the next group's record fetch overlaps the current group's gathers.
// AGG written in [B][N][24] layout so the pointwise kernel reads it fully coalesced.
__global__ __launch_bounds__(256) void spmm_kernel(const float* __restrict__ X,
                                                   const float* __restrict__ dinv,
                                                   const int* __restrict__ rowp,
                                                   const long long* __restrict__ ep,
                                                   float* __restrict__ agg) {
    int slice = blockIdx.x & 7;
    int grp   = blockIdx.x >> 3;
    int wave  = threadIdx.x >> 6;
    int lane  = threadIdx.x & 63;
    int d = __builtin_amdgcn_readfirstlane(grp * 4 + wave);  // wave-uniform row
    int c = slice * SCOLS + lane;
    bool act = lane < SCOLS;
    float di = dinv[d];
    float acc = act ? di * di * X[(size_t)d * NCOL + c] : 0.f;   // self-loop term
    int r0 = rowp[d];
    int r1 = rowp[d + 1];
    if (r0 < r1) {
        long long q[8], p[8];
        int e = r0;
        #pragma unroll
        for (int k = 0; k < 8; ++k) {
            int ix = e + k; ix = ix < r1 ? ix : r1 - 1;
            q[k] = ep[ix];
        }
        while (e < r1) {
            #pragma unroll
            for (int k = 0; k < 8; ++k) p[k] = q[k];
            int en = e + 8;
            if (en < r1) {
                #pragma unroll
                for (int k = 0; k < 8; ++k) {
                    int ix = en + k; ix = ix < r1 ? ix : r1 - 1;
                    q[k] = ep[ix];                 // prefetch next group (overlaps gathers)
                }
            }
            #pragma unroll
            for (int k = 0; k < 8; ++k) {
                if (e + k < r1) {                  // uniform branch
                    int s = (int)p[k];
                    float v = __int_as_float((int)(p[k] >> 32));
                    if (act) acc += v * X[(size_t)s * NCOL + c];
                }
            }
            e = en;
        }
    }
    if (act) {
        int b = slice * 2 + (lane >= 24 ? 1 : 0);
        int j = lane - (lane >= 24 ? 24 : 0);
        __builtin_nontemporal_store(acc, &agg[((size_t)b * NN + d) * 24 + j]);
    }
}

// ---------------- K8: fused GRU(H0=0) + attention accum + MLP + outputs ----------------
__global__ __launch_bounds__(256) void pointwise_kernel(const float* __restrict__ agg,
                                                        const float* __restrict__ cst,
                                                        const float* __restrict__ x,
                                                        const float* __restrict__ mask,
                                                        float* __restrict__ out) {
    __shared__ float C[396];
    int tid = threadIdx.x;
    for (int i = tid; i < 396; i += 256) C[i] = cst[i];
    __syncthreads();
    int idx = blockIdx.x * 256 + tid;     // 1250*256 == BB*NN exactly
    int b = idx / NN;
    int n = idx - b * NN;
    float A[24];
    const float4* ap = (const float4*)(agg + ((size_t)b * NN + n) * 24);  // coalesced: 96B/thread dense
    #pragma unroll
    for (int k = 0; k < 6; ++k) {
        float4 v = ap[k];
        A[4 * k + 0] = v.x; A[4 * k + 1] = v.y; A[4 * k + 2] = v.z; A[4 * k + 3] = v.w;
    }
    float h1[12];
    #pragma unroll
    for (int p = 0; p < 12; ++p) {
        float az0 = C[p], az1 = C[12 + p], czp = C[24 + p];
        float ah0 = C[36 + p], ah1 = C[48 + p], chp = C[60 + p];
        float hp = 0.f;
        #pragma unroll
        for (int t = 0; t < 12; ++t) {
            float a0 = A[2 * t], a1 = A[2 * t + 1];
            float z  = sigmoidf_(a0 * az0 + a1 * az1 + czp);
            float th = tanh_fast(a0 * ah0 + a1 * ah1 + chp);
            hp += C[72 + t] * ((1.f - z) * th);
        }
        h1[p] = fmaxf(hp, 0.f);
    }
    float h2[12];
    #pragma unroll
    for (int p = 0; p < 12; ++p) {
        float s = C[228 + p];
        #pragma unroll
        for (int q = 0; q < 12; ++q) s += h1[q] * C[84 + q * 12 + p];
        h2[p] = fmaxf(s, 0.f);
    }
    #pragma unroll
    for (int p = 0; p < 12; ++p) {
        float s = C[384 + p];
        #pragma unroll
        for (int q = 0; q < 12; ++q) s += h2[q] * C[240 + q * 12 + p];
        float imp = sigmoidf_(s);
        int o = (b * PP + p) * NN + n;
        float m = mask[o];
        float xv = x[o];
        out[o] = m * xv + (1.f - m) * imp;
        out[OUT_OFF + o] = imp;
    }
}

// ---------------- launcher ----------------
extern "C" void kernel_launch(void* const* d_in, const int* in_sizes, int n_in,
                              void* d_out, int out_size, void* d_ws, size_t ws_size,
                              hipStream_t stream) {
    const float* x     = (const float*)d_in[0];
    const float* mask  = (const float*)d_in[1];
    const float* noise = (const float*)d_in[2];
    const int*   ei    = (const int*)d_in[3];
    const float* ew    = (const float*)d_in[4];
    const float* Wz    = (const float*)d_in[5];
    const float* bz    = (const float*)d_in[6];
    // d_in[7]=Wr, d_in[8]=br unused (H0==0 -> R unused)
    const float* Wh    = (const float*)d_in[9];
    const float* bh    = (const float*)d_in[10];
    const float* Lzw   = (const float*)d_in[11];
    const float* Lzb   = (const float*)d_in[12];
    // d_in[13]=Lr_w, d_in[14]=Lr_b unused
    const float* Lhw   = (const float*)d_in[15];
    const float* Lhb   = (const float*)d_in[16];
    const float* att   = (const float*)d_in[17];
    const float* W1    = (const float*)d_in[18];
    const float* b1    = (const float*)d_in[19];
    const float* W2    = (const float*)d_in[20];
    const float* b2    = (const float*)d_in[21];
    float* out = (float*)d_out;

    // workspace carve-up
    float* Xf   = (float*)d_ws;                     // NN*NCOL
    float* AGG  = Xf + (size_t)NN * NCOL;           // BB*NN*24 == NN*NCOL floats, [B][N][24]
    long long* EPK = (long long*)(AGG + (size_t)NN * NCOL); // NE packed records (8B aligned)
    float* DEG  = (float*)(EPK + NE);               // NN
    float* DINV = DEG + NN;                         // NN
    float* CST  = DINV + NN;                        // 512
    int*   CNT  = (int*)(CST + 512);                // NN
    int*   ROWP = CNT + NN;                         // NN+1
    int*   CUR  = ROWP + NN + 1;                    // NN

    hipLaunchKernelGGL(init_kernel,    dim3((NN + 255) / 256), dim3(256), 0, stream, DEG, CNT);
    hipLaunchKernelGGL(degcnt_kernel,  dim3((NE + 255) / 256), dim3(256), 0, stream, ei, ew, DEG, CNT);
    hipLaunchKernelGGL(scan_kernel,    dim3(1), dim3(1024), 0, stream, CNT, DEG, ROWP, CUR, DINV);
    hipLaunchKernelGGL(scatter_kernel, dim3((NE + 255) / 256), dim3(256), 0, stream, ei, ew, DINV, CUR, (int2*)EPK);
    hipLaunchKernelGGL(prep_kernel,    dim3(1), dim3(256), 0, stream,
                       Wz, bz, Wh, bh, Lzw, Lzb, Lhw, Lhb, att, W1, b1, W2, b2, CST);
    hipLaunchKernelGGL(buildx_kernel,  dim3(NN / TILE), dim3(256), 0, stream, x, mask, noise, Xf);
    hipLaunchKernelGGL(spmm_kernel,    dim3(SLICES * NN / 4), dim3(256), 0, stream, Xf, DINV, ROWP, EPK, AGG);
    hipLaunchKernelGGL(pointwise_kernel, dim3((BB * NN) / 256), dim3(256), 0, stream, AGG, CST, x, mask, out);
}

// Round 4
// 405.455 us; speedup vs baseline: 1.0840x; 1.0840x over previous
//
#include <hip/hip_runtime.h>

#define NN 20000      // nodes
#define NE 320000     // edges
#define BB 16         // batch
#define PP 12         // periods
#define NCOL 384      // BB*PP*2 feature columns
#define OUT_OFF (BB*PP*NN)
#define SLICES 8
#define SCOLS 48      // 384/8 ; slice footprint 20000*48*4B = 3.84 MB <= 4 MB L2/XCD

// ---------------- small helpers ----------------
__device__ __forceinline__ float sigmoidf_(float v) {
    return __fdividef(1.f, 1.f + __expf(-v));
}
__device__ __forceinline__ float tanh_fast(float v) {
    v = fminf(fmaxf(v, -15.f), 15.f);
    float e = __expf(-2.f * v);
    return __fdividef(1.f - e, 1.f + e);
}

// ---------------- K1: init deg (self-loop weight 1) and counts ----------------
__global__ __launch_bounds__(256) void init_kernel(float* deg, int* cnt) {
    int i = blockIdx.x * 256 + threadIdx.x;
    if (i < NN) { deg[i] = 1.0f; cnt[i] = 0; }
}

// ---------------- K2: degree + per-dst edge count ----------------
__global__ __launch_bounds__(256) void degcnt_kernel(const int* __restrict__ ei,
                                                     const float* __restrict__ ew,
                                                     float* deg, int* cnt) {
    int e = blockIdx.x * 256 + threadIdx.x;
    if (e < NE) {
        int d = ei[NE + e];               // dst row of edge_index
        atomicAdd(&deg[d], ew[e]);
        atomicAdd(&cnt[d], 1);
    }
}

// ---------------- K3: fast single-pass scan (20 elems/thread) + dinv fused ----------------
__global__ __launch_bounds__(1024) void scan_kernel(const int* __restrict__ cnt,
                                                    const float* __restrict__ deg,
                                                    int* __restrict__ rowp,
                                                    int* __restrict__ cur,
                                                    float* __restrict__ dinv) {
    __shared__ int lds[1024];
    int tid = threadIdx.x;
    int base = tid * 20;                  // 1024*20 = 20480 >= NN
    int local[20];
    int s = 0;
    #pragma unroll
    for (int k = 0; k < 20; ++k) {
        int i = base + k;
        int v = (i < NN) ? cnt[i] : 0;
        local[k] = s;
        s += v;
    }
    lds[tid] = s;
    __syncthreads();
    for (int off = 1; off < 1024; off <<= 1) {
        int add = (tid >= off) ? lds[tid - off] : 0;
        __syncthreads();
        lds[tid] += add;
        __syncthreads();
    }
    int pre = (tid > 0) ? lds[tid - 1] : 0;
    #pragma unroll
    for (int k = 0; k < 20; ++k) {
        int i = base + k;
        if (i < NN) {
            int ex = pre + local[k];
            rowp[i] = ex; cur[i] = ex;
            float dg = deg[i];
            dinv[i] = dg > 0.f ? 1.0f / sqrtf(dg) : 0.f;
        }
    }
    if (tid == 0) rowp[NN] = lds[1023];   // == NE
}

// ---------------- K4: scatter edges into CSR as packed {col, normval} int2 ----------------
__global__ __launch_bounds__(256) void scatter_kernel(const int* __restrict__ ei,
                                                      const float* __restrict__ ew,
                                                      const float* __restrict__ dinv,
                                                      int* cur, int2* __restrict__ epk) {
    int e = blockIdx.x * 256 + threadIdx.x;
    if (e < NE) {
        int s = ei[e];
        int d = ei[NE + e];
        int pos = atomicAdd(&cur[d], 1);
        float v = dinv[s] * ew[e] * dinv[d];
        epk[pos] = make_int2(s, __float_as_int(v));
    }
}

// ---------------- K5: fold tiny matrices + softmax into const block ----------------
// layout: Az0[0:12] Az1[12:24] cz[24:36] Ah0[36:48] Ah1[48:60] ch[60:72]
//         probs[72:84] W1[84:228] b1[228:240] W2[240:384] b2[384:396]
__global__ __launch_bounds__(256) void prep_kernel(const float* __restrict__ Wz, const float* __restrict__ bz,
                                                   const float* __restrict__ Wh, const float* __restrict__ bh,
                                                   const float* __restrict__ Lzw, const float* __restrict__ Lzb,
                                                   const float* __restrict__ Lhw, const float* __restrict__ Lhb,
                                                   const float* __restrict__ att,
                                                   const float* __restrict__ W1, const float* __restrict__ b1,
                                                   const float* __restrict__ W2, const float* __restrict__ b2,
                                                   float* __restrict__ cst) {
    int t = threadIdx.x;
    if (t < PP) {
        int p = t;
        float az0 = 0.f, az1 = 0.f, cz = 0.f, ah0 = 0.f, ah1 = 0.f, ch = 0.f;
        for (int q = 0; q < PP; ++q) {
            float lz = Lzw[q * PP + p], lh = Lhw[q * PP + p];
            az0 += Wz[q] * lz;
            az1 += Wz[PP + q] * lz;
            cz  += bz[q] * lz;
            ah0 += Wh[q] * lh;
            ah1 += Wh[PP + q] * lh;
            ch  += bh[q] * lh;
        }
        cz += Lzb[p]; ch += Lhb[p];
        cst[p] = az0; cst[12 + p] = az1; cst[24 + p] = cz;
        cst[36 + p] = ah0; cst[48 + p] = ah1; cst[60 + p] = ch;
        float m = att[0];
        for (int q = 1; q < PP; ++q) m = fmaxf(m, att[q]);
        float ssum = 0.f;
        for (int q = 0; q < PP; ++q) ssum += __expf(att[q] - m);
        cst[72 + p] = __expf(att[p] - m) / ssum;
    }
    if (t < 144) { cst[84 + t] = W1[t]; cst[240 + t] = W2[t]; }
    if (t < PP) { cst[228 + t] = b1[t]; cst[384 + t] = b2[t]; }
}

// ---------------- K6: build X[N][384] (transposed, GAIN-filled) via LDS tiles ----------------
#define TILE 32
__global__ __launch_bounds__(256) void buildx_kernel(const float* __restrict__ x,
                                                     const float* __restrict__ mask,
                                                     const float* __restrict__ noise,
                                                     float* __restrict__ X) {
    __shared__ float tile[TILE][NCOL + 1];   // stride 385 -> conflict-free
    int tid = threadIdx.x;
    int n0 = blockIdx.x * TILE;
    int i = tid & 31;
    int prb = tid >> 5;
    #pragma unroll 4
    for (int it = 0; it < 24; ++it) {
        int pr = it * 8 + prb;                   // pr = b*12 + t
        int g = pr * NN + n0 + i;
        float m = mask[g];
        float xv = x[g];
        float nz = noise[g];
        float xf = m * xv + (1.f - m) * nz;
        int col = pr * 2;
        tile[i][col]     = xf;
        tile[i][col + 1] = m;
    }
    __syncthreads();
    #pragma unroll 4
    for (int it = 0; it < 48; ++it) {
        int idx = it * 256 + tid;
        int r = idx / NCOL;
        int c = idx - r * NCOL;
        X[(n0 + r) * NCOL + c] = tile[r][c];
    }
}

// ---------------- K7: XCD-partitioned gather SpMM, lane-parallel edge fetch ----------------
// slice = blockIdx & 7 -> each XCD's gathers confined to a 3.84 MB L2-resident X slice.
// Edge records: ONE coalesced per-lane load per 64 records (non-temporal, protects the
// X slice in L2), then __shfl broadcast per record; gathers issue in groups of 8
// independent loads. AGG written [B][N][24] so the pointwise kernel reads it coalesced.
__global__ __launch_bounds__(256) void spmm_kernel(const float* __restrict__ X,
                                                   const float* __restrict__ dinv,
                                                   const int* __restrict__ rowp,
                                                   const long long* __restrict__ ep,
                                                   float* __restrict__ agg) {
    int slice = blockIdx.x & 7;
    int grp   = blockIdx.x >> 3;
    int wave  = threadIdx.x >> 6;
    int lane  = threadIdx.x & 63;
    int d = grp * 4 + wave;                   // wave-uniform by construction
    int c = slice * SCOLS + lane;
    bool act = lane < SCOLS;
    float di = dinv[d];
    float acc = act ? di * di * X[(size_t)d * NCOL + c] : 0.f;   // self-loop term
    int r0 = rowp[d];
    int r1 = rowp[d + 1];
    for (int base = r0; base < r1; base += 64) {
        int ix = base + lane;
        long long rec = 0;
        if (ix < r1) rec = __builtin_nontemporal_load(ep + ix);  // coalesced 512B wave load
        int m = r1 - base; if (m > 64) m = 64;
        int k = 0;
        for (; k + 8 <= m; k += 8) {
            float vv[8], xv[8];
            #pragma unroll
            for (int j = 0; j < 8; ++j) {
                long long r = __shfl(rec, k + j);          // broadcast record k+j
                int s = (int)r;
                vv[j] = __int_as_float((int)(r >> 32));
                xv[j] = act ? X[(size_t)s * NCOL + c] : 0.f;   // 8 independent gathers
            }
            #pragma unroll
            for (int j = 0; j < 8; ++j) acc += vv[j] * xv[j];
        }
        for (; k < m; ++k) {
            long long r = __shfl(rec, k);
            int s = (int)r;
            float v = __int_as_float((int)(r >> 32));
            if (act) acc += v * X[(size_t)s * NCOL + c];
        }
    }
    if (act) {
        int b = slice * 2 + (lane >= 24 ? 1 : 0);
        int j = lane - (lane >= 24 ? 24 : 0);
        __builtin_nontemporal_store(acc, &agg[((size_t)b * NN + d) * 24 + j]);
    }
}

// ---------------- K8: fused GRU(H0=0) + attention accum + MLP + outputs ----------------
__global__ __launch_bounds__(256) void pointwise_kernel(const float* __restrict__ agg,
                                                        const float* __restrict__ cst,
                                                        const float* __restrict__ x,
                                                        const float* __restrict__ mask,
                                                        float* __restrict__ out) {
    __shared__ float C[396];
    int tid = threadIdx.x;
    for (int i = tid; i < 396; i += 256) C[i] = cst[i];
    __syncthreads();
    int idx = blockIdx.x * 256 + tid;     // 1250*256 == BB*NN exactly
    int b = idx / NN;
    int n = idx - b * NN;
    float A[24];
    const float4* ap = (const float4*)(agg + ((size_t)b * NN + n) * 24);  // coalesced 96B/thread
    #pragma unroll
    for (int k = 0; k < 6; ++k) {
        float4 v = ap[k];
        A[4 * k + 0] = v.x; A[4 * k + 1] = v.y; A[4 * k + 2] = v.z; A[4 * k + 3] = v.w;
    }
    float h1[12];
    #pragma unroll
    for (int p = 0; p < 12; ++p) {
        float az0 = C[p], az1 = C[12 + p], czp = C[24 + p];
        float ah0 = C[36 + p], ah1 = C[48 + p], chp = C[60 + p];
        float hp = 0.f;
        #pragma unroll
        for (int t = 0; t < 12; ++t) {
            float a0 = A[2 * t], a1 = A[2 * t + 1];
            float z  = sigmoidf_(a0 * az0 + a1 * az1 + czp);
            float th = tanh_fast(a0 * ah0 + a1 * ah1 + chp);
            hp += C[72 + t] * ((1.f - z) * th);
        }
        h1[p] = fmaxf(hp, 0.f);
    }
    float h2[12];
    #pragma unroll
    for (int p = 0; p < 12; ++p) {
        float s = C[228 + p];
        #pragma unroll
        for (int q = 0; q < 12; ++q) s += h1[q] * C[84 + q * 12 + p];
        h2[p] = fmaxf(s, 0.f);
    }
    #pragma unroll
    for (int p = 0; p < 12; ++p) {
        float s = C[384 + p];
        #pragma unroll
        for (int q = 0; q < 12; ++q) s += h2[q] * C[240 + q * 12 + p];
        float imp = sigmoidf_(s);
        int o = (b * PP + p) * NN + n;
        float m = mask[o];
        float xv = x[o];
        out[o] = m * xv + (1.f - m) * imp;
        out[OUT_OFF + o] = imp;
    }
}

// ---------------- launcher ----------------
extern "C" void kernel_launch(void* const* d_in, const int* in_sizes, int n_in,
                              void* d_out, int out_size, void* d_ws, size_t ws_size,
                              hipStream_t stream) {
    const float* x     = (const float*)d_in[0];
    const float* mask  = (const float*)d_in[1];
    const float* noise = (const float*)d_in[2];
    const int*   ei    = (const int*)d_in[3];
    const float* ew    = (const float*)d_in[4];
    const float* Wz    = (const float*)d_in[5];
    const float* bz    = (const float*)d_in[6];
    // d_in[7]=Wr, d_in[8]=br unused (H0==0 -> R unused)
    const float* Wh    = (const float*)d_in[9];
    const float* bh    = (const float*)d_in[10];
    const float* Lzw   = (const float*)d_in[11];
    const float* Lzb   = (const float*)d_in[12];
    // d_in[13]=Lr_w, d_in[14]=Lr_b unused
    const float* Lhw   = (const float*)d_in[15];
    const float* Lhb   = (const float*)d_in[16];
    const float* att   = (const float*)d_in[17];
    const float* W1    = (const float*)d_in[18];
    const float* b1    = (const float*)d_in[19];
    const float* W2    = (const float*)d_in[20];
    const float* b2    = (const float*)d_in[21];
    float* out = (float*)d_out;

    // workspace carve-up
    float* Xf   = (float*)d_ws;                     // NN*NCOL
    float* AGG  = Xf + (size_t)NN * NCOL;           // BB*NN*24 == NN*NCOL floats, [B][N][24]
    long long* EPK = (long long*)(AGG + (size_t)NN * NCOL); // NE packed records (8B aligned)
    float* DEG  = (float*)(EPK + NE);               // NN
    float* DINV = DEG + NN;                         // NN
    float* CST  = DINV + NN;                        // 512
    int*   CNT  = (int*)(CST + 512);                // NN
    int*   ROWP = CNT + NN;                         // NN+1
    int*   CUR  = ROWP + NN + 1;                    // NN

    hipLaunchKernelGGL(init_kernel,    dim3((NN + 255) / 256), dim3(256), 0, stream, DEG, CNT);
    hipLaunchKernelGGL(degcnt_kernel,  dim3((NE + 255) / 256), dim3(256), 0, stream, ei, ew, DEG, CNT);
    hipLaunchKernelGGL(scan_kernel,    dim3(1), dim3(1024), 0, stream, CNT, DEG, ROWP, CUR, DINV);
    hipLaunchKernelGGL(scatter_kernel, dim3((NE + 255) / 256), dim3(256), 0, stream, ei, ew, DINV, CUR, (int2*)EPK);
    hipLaunchKernelGGL(prep_kernel,    dim3(1), dim3(256), 0, stream,
                       Wz, bz, Wh, bh, Lzw, Lzb, Lhw, Lhb, att, W1, b1, W2, b2, CST);
    hipLaunchKernelGGL(buildx_kernel,  dim3(NN / TILE), dim3(256), 0, stream, x, mask, noise, Xf);
    hipLaunchKernelGGL(spmm_kernel,    dim3(SLICES * NN / 4), dim3(256), 0, stream, Xf, DINV, ROWP, EPK, AGG);
    hipLaunchKernelGGL(pointwise_kernel, dim3((BB * NN) / 256), dim3(256), 0, stream, AGG, CST, x, mask, out);
}

// Round 5
// 379.783 us; speedup vs baseline: 1.1573x; 1.0676x over previous
//
#include <hip/hip_runtime.h>

#define NN 20000      // nodes
#define NE 320000     // edges
#define BB 16         // batch
#define PP 12         // periods
#define NCOL 384      // BB*PP*2 feature columns
#define OUT_OFF (BB*PP*NN)
#define SLICES 8
#define SCOLS 48      // 384/8 ; slice footprint 20000*48*4B = 3.84 MB <= 4 MB L2/XCD

// ---------------- small helpers ----------------
__device__ __forceinline__ float sigmoidf_(float v) {
    return __fdividef(1.f, 1.f + __expf(-v));
}
__device__ __forceinline__ float tanh_fast(float v) {
    v = fminf(fmaxf(v, -15.f), 15.f);
    float e = __expf(-2.f * v);
    return __fdividef(1.f - e, 1.f + e);
}

// ---------------- K1: degree + per-dst edge count (DEG/CNT pre-zeroed by memset) ----------------
__global__ __launch_bounds__(256) void degcnt_kernel(const int* __restrict__ ei,
                                                     const float* __restrict__ ew,
                                                     float* deg, int* cnt) {
    int e = blockIdx.x * 256 + threadIdx.x;
    if (e < NE) {
        int d = ei[NE + e];               // dst row of edge_index
        atomicAdd(&deg[d], ew[e]);
        atomicAdd(&cnt[d], 1);
    }
}

// ---------------- K2: block0 = scan(counts)+dinv ; block1 = prep (independent) ----------------
// cst layout: Az0[0:12] Az1[12:24] cz[24:36] Ah0[36:48] Ah1[48:60] ch[60:72]
//             probs[72:84] W1[84:228] b1[228:240] W2[240:384] b2[384:396]
__global__ __launch_bounds__(1024) void scanprep_kernel(const int* __restrict__ cnt,
                                                        const float* __restrict__ deg,
                                                        int* __restrict__ rowp,
                                                        int* __restrict__ cur,
                                                        float* __restrict__ dinv,
                                                        const float* __restrict__ Wz, const float* __restrict__ bz,
                                                        const float* __restrict__ Wh, const float* __restrict__ bh,
                                                        const float* __restrict__ Lzw, const float* __restrict__ Lzb,
                                                        const float* __restrict__ Lhw, const float* __restrict__ Lhb,
                                                        const float* __restrict__ att,
                                                        const float* __restrict__ W1, const float* __restrict__ b1,
                                                        const float* __restrict__ W2, const float* __restrict__ b2,
                                                        float* __restrict__ cst) {
    int tid = threadIdx.x;
    if (blockIdx.x == 1) {                // ---- prep (tiny) ----
        if (tid < PP) {
            int p = tid;
            float az0 = 0.f, az1 = 0.f, cz = 0.f, ah0 = 0.f, ah1 = 0.f, ch = 0.f;
            for (int q = 0; q < PP; ++q) {
                float lz = Lzw[q * PP + p], lh = Lhw[q * PP + p];
                az0 += Wz[q] * lz;
                az1 += Wz[PP + q] * lz;
                cz  += bz[q] * lz;
                ah0 += Wh[q] * lh;
                ah1 += Wh[PP + q] * lh;
                ch  += bh[q] * lh;
            }
            cz += Lzb[p]; ch += Lhb[p];
            cst[p] = az0; cst[12 + p] = az1; cst[24 + p] = cz;
            cst[36 + p] = ah0; cst[48 + p] = ah1; cst[60 + p] = ch;
            float m = att[0];
            for (int q = 1; q < PP; ++q) m = fmaxf(m, att[q]);
            float ssum = 0.f;
            for (int q = 0; q < PP; ++q) ssum += __expf(att[q] - m);
            cst[72 + p] = __expf(att[p] - m) / ssum;
        }
        if (tid < 144) { cst[84 + tid] = W1[tid]; cst[240 + tid] = W2[tid]; }
        if (tid < PP)  { cst[228 + tid] = b1[tid]; cst[384 + tid] = b2[tid]; }
        return;
    }
    // ---- scan ----
    __shared__ int lds[1024];
    int base = tid * 20;                  // 1024*20 = 20480 >= NN
    int local[20];
    int s = 0;
    #pragma unroll
    for (int k = 0; k < 20; ++k) {
        int i = base + k;
        int v = (i < NN) ? cnt[i] : 0;
        local[k] = s;
        s += v;
    }
    lds[tid] = s;
    __syncthreads();
    for (int off = 1; off < 1024; off <<= 1) {
        int add = (tid >= off) ? lds[tid - off] : 0;
        __syncthreads();
        lds[tid] += add;
        __syncthreads();
    }
    int pre = (tid > 0) ? lds[tid - 1] : 0;
    #pragma unroll
    for (int k = 0; k < 20; ++k) {
        int i = base + k;
        if (i < NN) {
            int ex = pre + local[k];
            rowp[i] = ex; cur[i] = ex;
            dinv[i] = __frsqrt_rn(deg[i] + 1.0f);   // +1 = self-loop weight, always > 0
        }
    }
    if (tid == 0) rowp[NN] = lds[1023];   // == NE
}

// ---------------- K3: scatter edges into CSR as packed {col, normval} ----------------
__global__ __launch_bounds__(256) void scatter_kernel(const int* __restrict__ ei,
                                                      const float* __restrict__ ew,
                                                      const float* __restrict__ dinv,
                                                      int* cur, int2* __restrict__ epk) {
    int e = blockIdx.x * 256 + threadIdx.x;
    if (e < NE) {
        int s = ei[e];
        int d = ei[NE + e];
        int pos = atomicAdd(&cur[d], 1);
        float v = dinv[s] * ew[e] * dinv[d];
        epk[pos] = make_int2(s, __float_as_int(v));
    }
}

// ---------------- K4: build X[N][384] (transposed, GAIN-filled) via LDS tiles ----------------
// grid (625, 4): blockIdx.y picks 48 of the 192 (b,t) pairs -> 2500 blocks for latency hiding
#define TILE 32
__global__ __launch_bounds__(256) void buildx_kernel(const float* __restrict__ x,
                                                     const float* __restrict__ mask,
                                                     const float* __restrict__ noise,
                                                     float* __restrict__ X) {
    __shared__ float tile[TILE][97];         // 96 local cols + 1 pad -> conflict-free
    int tid = threadIdx.x;
    int n0 = blockIdx.x * TILE;
    int pr0 = blockIdx.y * 48;               // 48 (b,t) pairs per block
    int i = tid & 31;
    int prb = tid >> 5;
    #pragma unroll
    for (int it = 0; it < 6; ++it) {         // 48 pairs / 8
        int prl = it * 8 + prb;              // local pair index 0..47
        int pr = pr0 + prl;
        int g = pr * NN + n0 + i;
        float m = mask[g];
        float xv = x[g];
        float nz = noise[g];
        float xf = m * xv + (1.f - m) * nz;  // GAIN fill (mask is exactly 0/1)
        tile[i][prl * 2]     = xf;
        tile[i][prl * 2 + 1] = m;
    }
    __syncthreads();
    int c0 = blockIdx.y * 96;
    #pragma unroll
    for (int it = 0; it < 12; ++it) {        // 32*96 / 256
        int idx = it * 256 + tid;
        int r = idx / 96;
        int c = idx - r * 96;
        X[(n0 + r) * NCOL + c0 + c] = tile[r][c];
    }
}

// ---------------- K5: XCD-partitioned gather SpMM, 4 rows/wave for 32-deep MLP ----------------
// slice = blockIdx & 7 -> gathers confined to a 3.84 MB L2-resident X column slice.
// Lanes 0..31 fetch 4 rows x 8 edge records in ONE coalesced NT load (double-buffered);
// records broadcast via __shfl; 32 independent gathers in flight per group.
// Invalid slots carry rec=0 -> weight 0, gather row 0 (L2-hot): no branches in hot loop.
__global__ __launch_bounds__(256) void spmm_kernel(const float* __restrict__ X,
                                                   const float* __restrict__ dinv,
                                                   const int* __restrict__ rowp,
                                                   const long long* __restrict__ ep,
                                                   float* __restrict__ agg) {
    int slice = blockIdx.x & 7;
    int grp   = blockIdx.x >> 3;              // 0..1249
    int wave  = threadIdx.x >> 6;
    int lane  = threadIdx.x & 63;
    int d0 = (grp * 4 + wave) * 4;            // 4 rows per wave
    int c  = slice * SCOLS + lane;
    bool act = lane < SCOLS;
    int cg = act ? c : slice * SCOLS;         // clamp inactive lanes (no OOB)

    // wave-uniform row ranges
    int r0[4], r1[4];
    float acc[4];
    #pragma unroll
    for (int r = 0; r < 4; ++r) {
        int d = d0 + r;
        r0[r] = rowp[d];
        r1[r] = rowp[d + 1];
        float di = dinv[d];
        acc[r] = act ? di * di * X[(size_t)d * NCOL + c] : 0.f;   // self-loop term
    }
    int maxdeg = max(max(r1[0] - r0[0], r1[1] - r0[1]), max(r1[2] - r0[2], r1[3] - r0[3]));

    // per-lane fetch duty: lanes 0..31, row = lane>>3, j = lane&7
    int fr0 = 0, fr1 = 0;
    if (lane < 32) {
        int fd = d0 + (lane >> 3);
        fr0 = rowp[fd];
        fr1 = rowp[fd + 1];
    }
    int fj = lane & 7;

    long long cur = 0;
    {   // prologue: fetch group 0
        int e = fr0 + fj;
        if (lane < 32 && e < fr1) cur = __builtin_nontemporal_load(ep + e);
    }
    for (int off = 0; off < maxdeg; off += 8) {
        long long nxt = 0;
        {   // prefetch next group (overlaps with this group's gathers)
            int e = fr0 + off + 8 + fj;
            if (lane < 32 && e < fr1) nxt = __builtin_nontemporal_load(ep + e);
        }
        float vv[4][8], xv[4][8];
        #pragma unroll
        for (int r = 0; r < 4; ++r) {
            #pragma unroll
            for (int j = 0; j < 8; ++j) {
                long long rec = __shfl(cur, r * 8 + j);
                int s = (int)rec;
                vv[r][j] = __int_as_float((int)(rec >> 32));
                xv[r][j] = X[(size_t)s * NCOL + cg];      // 32 independent gathers
            }
        }
        #pragma unroll
        for (int r = 0; r < 4; ++r)
            #pragma unroll
            for (int j = 0; j < 8; ++j)
                acc[r] += vv[r][j] * xv[r][j];
        cur = nxt;
    }
    if (act) {
        int b = slice * 2 + (lane >= 24 ? 1 : 0);
        int j = lane - (lane >= 24 ? 24 : 0);
        #pragma unroll
        for (int r = 0; r < 4; ++r)
            __builtin_nontemporal_store(acc[r], &agg[((size_t)b * NN + d0 + r) * 24 + j]);
    }
}

// ---------------- K6: fused GRU(H0=0) + attention accum + MLP + outputs ----------------
__global__ __launch_bounds__(256) void pointwise_kernel(const float* __restrict__ agg,
                                                        const float* __restrict__ cst,
                                                        const float* __restrict__ x,
                                                        const float* __restrict__ mask,
                                                        float* __restrict__ out) {
    __shared__ float C[396];
    int tid = threadIdx.x;
    for (int i = tid; i < 396; i += 256) C[i] = cst[i];
    __syncthreads();
    int idx = blockIdx.x * 256 + tid;     // 1250*256 == BB*NN exactly
    int b = idx / NN;
    int n = idx - b * NN;
    float A[24];
    const float4* ap = (const float4*)(agg + ((size_t)b * NN + n) * 24);  // coalesced 96B/thread
    #pragma unroll
    for (int k = 0; k < 6; ++k) {
        float4 v = ap[k];
        A[4 * k + 0] = v.x; A[4 * k + 1] = v.y; A[4 * k + 2] = v.z; A[4 * k + 3] = v.w;
    }
    float h1[12];
    #pragma unroll
    for (int p = 0; p < 12; ++p) {
        float az0 = C[p], az1 = C[12 + p], czp = C[24 + p];
        float ah0 = C[36 + p], ah1 = C[48 + p], chp = C[60 + p];
        float hp = 0.f;
        #pragma unroll
        for (int t = 0; t < 12; ++t) {
            float a0 = A[2 * t], a1 = A[2 * t + 1];
            float z  = sigmoidf_(a0 * az0 + a1 * az1 + czp);
            float th = tanh_fast(a0 * ah0 + a1 * ah1 + chp);
            hp += C[72 + t] * ((1.f - z) * th);
        }
        h1[p] = fmaxf(hp, 0.f);
    }
    float h2[12];
    #pragma unroll
    for (int p = 0; p < 12; ++p) {
        float s = C[228 + p];
        #pragma unroll
        for (int q = 0; q < 12; ++q) s += h1[q] * C[84 + q * 12 + p];
        h2[p] = fmaxf(s, 0.f);
    }
    #pragma unroll
    for (int p = 0; p < 12; ++p) {
        float s = C[384 + p];
        #pragma unroll
        for (int q = 0; q < 12; ++q) s += h2[q] * C[240 + q * 12 + p];
        float imp = sigmoidf_(s);
        int o = (b * PP + p) * NN + n;
        float m = mask[o];
        float xv = x[o];
        out[o] = m * xv + (1.f - m) * imp;
        out[OUT_OFF + o] = imp;
    }
}

// ---------------- launcher ----------------
extern "C" void kernel_launch(void* const* d_in, const int* in_sizes, int n_in,
                              void* d_out, int out_size, void* d_ws, size_t ws_size,
                              hipStream_t stream) {
    const float* x     = (const float*)d_in[0];
    const float* mask  = (const float*)d_in[1];
    const float* noise = (const float*)d_in[2];
    const int*   ei    = (const int*)d_in[3];
    const float* ew    = (const float*)d_in[4];
    const float* Wz    = (const float*)d_in[5];
    const float* bz    = (const float*)d_in[6];
    // d_in[7]=Wr, d_in[8]=br unused (H0==0 -> R unused)
    const float* Wh    = (const float*)d_in[9];
    const float* bh    = (const float*)d_in[10];
    const float* Lzw   = (const float*)d_in[11];
    const float* Lzb   = (const float*)d_in[12];
    // d_in[13]=Lr_w, d_in[14]=Lr_b unused
    const float* Lhw   = (const float*)d_in[15];
    const float* Lhb   = (const float*)d_in[16];
    const float* att   = (const float*)d_in[17];
    const float* W1    = (const float*)d_in[18];
    const float* b1    = (const float*)d_in[19];
    const float* W2    = (const float*)d_in[20];
    const float* b2    = (const float*)d_in[21];
    float* out = (float*)d_out;

    // workspace carve-up (DEG and CNT adjacent -> single memset)
    float* Xf   = (float*)d_ws;                     // NN*NCOL floats
    float* AGG  = Xf + (size_t)NN * NCOL;           // BB*NN*24 floats, [B][N][24]
    long long* EPK = (long long*)(AGG + (size_t)NN * NCOL); // NE packed records
    float* DEG  = (float*)(EPK + NE);               // NN floats (edge-weight sum, no self-loop)
    int*   CNT  = (int*)(DEG + NN);                 // NN ints
    float* DINV = (float*)(CNT + NN);               // NN
    float* CST  = DINV + NN;                        // 512
    int*   ROWP = (int*)(CST + 512);                // NN+1
    int*   CUR  = ROWP + NN + 1;                    // NN

    hipMemsetAsync(DEG, 0, (size_t)2 * NN * 4, stream);      // zero DEG + CNT in one dispatch
    hipLaunchKernelGGL(degcnt_kernel,  dim3((NE + 255) / 256), dim3(256), 0, stream, ei, ew, DEG, CNT);
    hipLaunchKernelGGL(scanprep_kernel, dim3(2), dim3(1024), 0, stream, CNT, DEG, ROWP, CUR, DINV,
                       Wz, bz, Wh, bh, Lzw, Lzb, Lhw, Lhb, att, W1, b1, W2, b2, CST);
    hipLaunchKernelGGL(scatter_kernel, dim3((NE + 255) / 256), dim3(256), 0, stream, ei, ew, DINV, CUR, (int2*)EPK);
    hipLaunchKernelGGL(buildx_kernel,  dim3(NN / TILE, 4), dim3(256), 0, stream, x, mask, noise, Xf);
    hipLaunchKernelGGL(spmm_kernel,    dim3(SLICES * NN / 16), dim3(256), 0, stream, Xf, DINV, ROWP, EPK, AGG);
    hipLaunchKernelGGL(pointwise_kernel, dim3((BB * NN) / 256), dim3(256), 0, stream, AGG, CST, x, mask, out);
}

// Round 6
// 373.097 us; speedup vs baseline: 1.1780x; 1.0179x over previous
//
#include <hip/hip_runtime.h>

#define NN 20000      // nodes
#define NE 320000     // edges
#define BB 16         // batch
#define PP 12         // periods
#define NCOL 384      // BB*PP*2 feature columns
#define OUT_OFF (BB*PP*NN)
#define SLICES 8
#define SCOLS 48      // 384/8 ; slice = contiguous [NN][48] block = 3.84 MB, L2-resident per XCD

// ---------------- small helpers ----------------
__device__ __forceinline__ float sigmoidf_(float v) {
    return __fdividef(1.f, 1.f + __expf(-v));
}
__device__ __forceinline__ float tanh_fast(float v) {
    v = fminf(fmaxf(v, -15.f), 15.f);
    float e = __expf(-2.f * v);
    return __fdividef(1.f - e, 1.f + e);
}

// ---------------- K1: fused degcnt (blocks 0..1249) + buildx (blocks 1250..3749) ----------------
// degcnt: degree + per-dst edge count (DEG/CNT pre-zeroed by memset).
// buildx: X in SLICE-MAJOR layout X[slice][n][48]: each slice contiguous ->
//         192B row stride -> L2 set indices uniform (fixes the 1536B-stride set-conflict
//         pattern that thrashed L2: gcd(12,2048)=4 put 20000 rows into 512 sets).
#define TILE 32
__global__ __launch_bounds__(256) void degbuild_kernel(const int* __restrict__ ei,
                                                       const float* __restrict__ ew,
                                                       float* deg, int* cnt,
                                                       const float* __restrict__ x,
                                                       const float* __restrict__ mask,
                                                       const float* __restrict__ noise,
                                                       float* __restrict__ X) {
    if (blockIdx.x < 1250) {               // ---- degcnt ----
        int e = blockIdx.x * 256 + threadIdx.x;
        if (e < NE) {
            int d = ei[NE + e];            // dst row of edge_index
            atomicAdd(&deg[d], ew[e]);
            atomicAdd(&cnt[d], 1);
        }
        return;
    }
    // ---- buildx ----
    __shared__ float tile[TILE][97];       // 96 local cols + 1 pad -> conflict-free
    int bid = blockIdx.x - 1250;           // 0..2499
    int bx = bid % 625;
    int by = bid / 625;                    // 0..3 : 48 (b,t) pairs = 2 slices per by
    int tid = threadIdx.x;
    int n0 = bx * TILE;
    int pr0 = by * 48;
    int i = tid & 31;
    int prb = tid >> 5;
    #pragma unroll
    for (int it = 0; it < 6; ++it) {       // 48 pairs / 8
        int prl = it * 8 + prb;            // local pair index 0..47
        int pr = pr0 + prl;                // pr = b*12 + t
        int g = pr * NN + n0 + i;
        float m = mask[g];
        float xv = x[g];
        float nz = noise[g];
        float xf = m * xv + (1.f - m) * nz;   // GAIN fill (mask is exactly 0/1)
        tile[i][prl * 2]     = xf;
        tile[i][prl * 2 + 1] = m;
    }
    __syncthreads();
    #pragma unroll
    for (int it = 0; it < 12; ++it) {      // 32*96 / 256
        int idx = it * 256 + tid;
        int r = idx / 96;
        int c = idx - r * 96;              // 0..95 ; slice-local col = c%48
        int slice = by * 2 + (c >= 48 ? 1 : 0);
        int lc = c - (c >= 48 ? 48 : 0);
        X[((size_t)slice * NN + n0 + r) * SCOLS + lc] = tile[r][c];
    }
}

// ---------------- K2: block0 = scan(counts)+dinv ; block1 = prep ----------------
// cst layout: Az0[0:12] Az1[12:24] cz[24:36] Ah0[36:48] Ah1[48:60] ch[60:72]
//             probs[72:84] W1[84:228] b1[228:240] W2[240:384] b2[384:396]
__global__ __launch_bounds__(1024) void scanprep_kernel(const int* __restrict__ cnt,
                                                        const float* __restrict__ deg,
                                                        int* __restrict__ rowp,
                                                        int* __restrict__ cur,
                                                        float* __restrict__ dinv,
                                                        const float* __restrict__ Wz, const float* __restrict__ bz,
                                                        const float* __restrict__ Wh, const float* __restrict__ bh,
                                                        const float* __restrict__ Lzw, const float* __restrict__ Lzb,
                                                        const float* __restrict__ Lhw, const float* __restrict__ Lhb,
                                                        const float* __restrict__ att,
                                                        const float* __restrict__ W1, const float* __restrict__ b1,
                                                        const float* __restrict__ W2, const float* __restrict__ b2,
                                                        float* __restrict__ cst) {
    int tid = threadIdx.x;
    if (blockIdx.x == 1) {                 // ---- prep (tiny) ----
        if (tid < PP) {
            int p = tid;
            float az0 = 0.f, az1 = 0.f, cz = 0.f, ah0 = 0.f, ah1 = 0.f, ch = 0.f;
            for (int q = 0; q < PP; ++q) {
                float lz = Lzw[q * PP + p], lh = Lhw[q * PP + p];
                az0 += Wz[q] * lz;
                az1 += Wz[PP + q] * lz;
                cz  += bz[q] * lz;
                ah0 += Wh[q] * lh;
                ah1 += Wh[PP + q] * lh;
                ch  += bh[q] * lh;
            }
            cz += Lzb[p]; ch += Lhb[p];
            cst[p] = az0; cst[12 + p] = az1; cst[24 + p] = cz;
            cst[36 + p] = ah0; cst[48 + p] = ah1; cst[60 + p] = ch;
            float m = att[0];
            for (int q = 1; q < PP; ++q) m = fmaxf(m, att[q]);
            float ssum = 0.f;
            for (int q = 0; q < PP; ++q) ssum += __expf(att[q] - m);
            cst[72 + p] = __expf(att[p] - m) / ssum;
        }
        if (tid < 144) { cst[84 + tid] = W1[tid]; cst[240 + tid] = W2[tid]; }
        if (tid < PP)  { cst[228 + tid] = b1[tid]; cst[384 + tid] = b2[tid]; }
        return;
    }
    // ---- scan ----
    __shared__ int lds[1024];
    int base = tid * 20;                   // 1024*20 = 20480 >= NN
    int local[20];
    int s = 0;
    #pragma unroll
    for (int k = 0; k < 20; ++k) {
        int i = base + k;
        int v = (i < NN) ? cnt[i] : 0;
        local[k] = s;
        s += v;
    }
    lds[tid] = s;
    __syncthreads();
    for (int off = 1; off < 1024; off <<= 1) {
        int add = (tid >= off) ? lds[tid - off] : 0;
        __syncthreads();
        lds[tid] += add;
        __syncthreads();
    }
    int pre = (tid > 0) ? lds[tid - 1] : 0;
    #pragma unroll
    for (int k = 0; k < 20; ++k) {
        int i = base + k;
        if (i < NN) {
            int ex = pre + local[k];
            rowp[i] = ex; cur[i] = ex;
            dinv[i] = __frsqrt_rn(deg[i] + 1.0f);   // +1 = self-loop weight, always > 0
        }
    }
    if (tid == 0) rowp[NN] = lds[1023];    // == NE
}

// ---------------- K3: scatter edges into CSR as packed {col, normval} ----------------
__global__ __launch_bounds__(256) void scatter_kernel(const int* __restrict__ ei,
                                                      const float* __restrict__ ew,
                                                      const float* __restrict__ dinv,
                                                      int* cur, int2* __restrict__ epk) {
    int e = blockIdx.x * 256 + threadIdx.x;
    if (e < NE) {
        int s = ei[e];
        int d = ei[NE + e];
        int pos = atomicAdd(&cur[d], 1);
        float v = dinv[s] * ew[e] * dinv[d];
        epk[pos] = make_int2(s, __float_as_int(v));
    }
}

// ---------------- K4: XCD-partitioned gather SpMM on slice-major X ----------------
// slice = blockIdx & 7 -> XCD id (round-robin dispatch); Xs = contiguous 3.84 MB,
// set-conflict-free -> stays L2-resident. 4 rows/wave, 32 independent gathers in
// flight, edge records NT-loaded 2 groups ahead (covers ~900cy HBM latency).
__global__ __launch_bounds__(256) void spmm_kernel(const float* __restrict__ X,
                                                   const float* __restrict__ dinv,
                                                   const int* __restrict__ rowp,
                                                   const long long* __restrict__ ep,
                                                   float* __restrict__ agg) {
    int slice = blockIdx.x & 7;
    int grp   = blockIdx.x >> 3;               // 0..1249
    int wave  = threadIdx.x >> 6;
    int lane  = threadIdx.x & 63;
    int d0 = (grp * 4 + wave) * 4;             // 4 rows per wave
    bool act = lane < SCOLS;
    int cg = act ? lane : 0;                   // clamped col for inactive lanes
    const float* Xs = X + (size_t)slice * NN * SCOLS;

    int r0[4], r1[4];
    float acc[4];
    #pragma unroll
    for (int r = 0; r < 4; ++r) {
        int d = d0 + r;
        r0[r] = rowp[d];
        r1[r] = rowp[d + 1];
        float di = dinv[d];
        acc[r] = act ? di * di * Xs[(size_t)d * SCOLS + cg] : 0.f;   // self-loop term
    }
    int maxdeg = max(max(r1[0] - r0[0], r1[1] - r0[1]), max(r1[2] - r0[2], r1[3] - r0[3]));

    // per-lane fetch duty: lanes 0..31, row = lane>>3, j = lane&7
    int fr0 = 0, fr1 = 0;
    if (lane < 32) {
        int fd = d0 + (lane >> 3);
        fr0 = rowp[fd];
        fr1 = rowp[fd + 1];
    }
    int fj = lane & 7;

    long long cur = 0, nxt = 0;
    {   // prologue: fetch groups 0 and 1 (distance-2 pipeline)
        int e0 = fr0 + fj;
        if (lane < 32 && e0 < fr1) cur = __builtin_nontemporal_load(ep + e0);
        int e1 = fr0 + 8 + fj;
        if (lane < 32 && e1 < fr1) nxt = __builtin_nontemporal_load(ep + e1);
    }
    for (int off = 0; off < maxdeg; off += 8) {
        long long nx2 = 0;
        {   // prefetch group off/8 + 2
            int e = fr0 + off + 16 + fj;
            if (lane < 32 && e < fr1) nx2 = __builtin_nontemporal_load(ep + e);
        }
        float vv[4][8], xv[4][8];
        #pragma unroll
        for (int r = 0; r < 4; ++r) {
            #pragma unroll
            for (int j = 0; j < 8; ++j) {
                long long rec = __shfl(cur, r * 8 + j);   // broadcast record
                int s = (int)rec;                          // invalid slots: s=0 (L2-hot), v=0
                vv[r][j] = __int_as_float((int)(rec >> 32));
                xv[r][j] = Xs[(size_t)s * SCOLS + cg];    // 32 independent L2-hit gathers
            }
        }
        #pragma unroll
        for (int r = 0; r < 4; ++r)
            #pragma unroll
            for (int j = 0; j < 8; ++j)
                acc[r] += vv[r][j] * xv[r][j];
        cur = nxt; nxt = nx2;
    }
    if (act) {
        int b = slice * 2 + (lane >= 24 ? 1 : 0);
        int j = lane - (lane >= 24 ? 24 : 0);
        #pragma unroll
        for (int r = 0; r < 4; ++r)
            __builtin_nontemporal_store(acc[r], &agg[((size_t)b * NN + d0 + r) * 24 + j]);
    }
}

// ---------------- K5: fused GRU(H0=0) + attention accum + MLP + outputs ----------------
__global__ __launch_bounds__(256) void pointwise_kernel(const float* __restrict__ agg,
                                                        const float* __restrict__ cst,
                                                        const float* __restrict__ x,
                                                        const float* __restrict__ mask,
                                                        float* __restrict__ out) {
    __shared__ float C[396];
    int tid = threadIdx.x;
    for (int i = tid; i < 396; i += 256) C[i] = cst[i];
    __syncthreads();
    int idx = blockIdx.x * 256 + tid;     // 1250*256 == BB*NN exactly
    int b = idx / NN;
    int n = idx - b * NN;
    float A[24];
    const float4* ap = (const float4*)(agg + ((size_t)b * NN + n) * 24);  // coalesced 96B/thread
    #pragma unroll
    for (int k = 0; k < 6; ++k) {
        float4 v = ap[k];
        A[4 * k + 0] = v.x; A[4 * k + 1] = v.y; A[4 * k + 2] = v.z; A[4 * k + 3] = v.w;
    }
    float h1[12];
    #pragma unroll
    for (int p = 0; p < 12; ++p) {
        float az0 = C[p], az1 = C[12 + p], czp = C[24 + p];
        float ah0 = C[36 + p], ah1 = C[48 + p], chp = C[60 + p];
        float hp = 0.f;
        #pragma unroll
        for (int t = 0; t < 12; ++t) {
            float a0 = A[2 * t], a1 = A[2 * t + 1];
            float z  = sigmoidf_(a0 * az0 + a1 * az1 + czp);
            float th = tanh_fast(a0 * ah0 + a1 * ah1 + chp);
            hp += C[72 + t] * ((1.f - z) * th);
        }
        h1[p] = fmaxf(hp, 0.f);
    }
    float h2[12];
    #pragma unroll
    for (int p = 0; p < 12; ++p) {
        float s = C[228 + p];
        #pragma unroll
        for (int q = 0; q < 12; ++q) s += h1[q] * C[84 + q * 12 + p];
        h2[p] = fmaxf(s, 0.f);
    }
    #pragma unroll
    for (int p = 0; p < 12; ++p) {
        float s = C[384 + p];
        #pragma unroll
        for (int q = 0; q < 12; ++q) s += h2[q] * C[240 + q * 12 + p];
        float imp = sigmoidf_(s);
        int o = (b * PP + p) * NN + n;
        float m = mask[o];
        float xv = x[o];
        out[o] = m * xv + (1.f - m) * imp;
        out[OUT_OFF + o] = imp;
    }
}

// ---------------- launcher ----------------
extern "C" void kernel_launch(void* const* d_in, const int* in_sizes, int n_in,
                              void* d_out, int out_size, void* d_ws, size_t ws_size,
                              hipStream_t stream) {
    const float* x     = (const float*)d_in[0];
    const float* mask  = (const float*)d_in[1];
    const float* noise = (const float*)d_in[2];
    const int*   ei    = (const int*)d_in[3];
    const float* ew    = (const float*)d_in[4];
    const float* Wz    = (const float*)d_in[5];
    const float* bz    = (const float*)d_in[6];
    // d_in[7]=Wr, d_in[8]=br unused (H0==0 -> R unused)
    const float* Wh    = (const float*)d_in[9];
    const float* bh    = (const float*)d_in[10];
    const float* Lzw   = (const float*)d_in[11];
    const float* Lzb   = (const float*)d_in[12];
    // d_in[13]=Lr_w, d_in[14]=Lr_b unused
    const float* Lhw   = (const float*)d_in[15];
    const float* Lhb   = (const float*)d_in[16];
    const float* att   = (const float*)d_in[17];
    const float* W1    = (const float*)d_in[18];
    const float* b1    = (const float*)d_in[19];
    const float* W2    = (const float*)d_in[20];
    const float* b2    = (const float*)d_in[21];
    float* out = (float*)d_out;

    // workspace carve-up (DEG and CNT adjacent -> single memset)
    float* Xf   = (float*)d_ws;                     // SLICES*NN*SCOLS floats (slice-major)
    float* AGG  = Xf + (size_t)NN * NCOL;           // BB*NN*24 floats, [B][N][24]
    long long* EPK = (long long*)(AGG + (size_t)NN * NCOL); // NE packed records
    float* DEG  = (float*)(EPK + NE);               // NN floats (edge-weight sum, no self-loop)
    int*   CNT  = (int*)(DEG + NN);                 // NN ints
    float* DINV = (float*)(CNT + NN);               // NN
    float* CST  = DINV + NN;                        // 512
    int*   ROWP = (int*)(CST + 512);                // NN+1
    int*   CUR  = ROWP + NN + 1;                    // NN

    hipMemsetAsync(DEG, 0, (size_t)2 * NN * 4, stream);      // zero DEG + CNT in one dispatch
    hipLaunchKernelGGL(degbuild_kernel, dim3(1250 + 2500), dim3(256), 0, stream,
                       ei, ew, DEG, CNT, x, mask, noise, Xf);
    hipLaunchKernelGGL(scanprep_kernel, dim3(2), dim3(1024), 0, stream, CNT, DEG, ROWP, CUR, DINV,
                       Wz, bz, Wh, bh, Lzw, Lzb, Lhw, Lhb, att, W1, b1, W2, b2, CST);
    hipLaunchKernelGGL(scatter_kernel, dim3((NE + 255) / 256), dim3(256), 0, stream, ei, ew, DINV, CUR, (int2*)EPK);
    hipLaunchKernelGGL(spmm_kernel,    dim3(SLICES * NN / 16), dim3(256), 0, stream, Xf, DINV, ROWP, EPK, AGG);
    hipLaunchKernelGGL(pointwise_kernel, dim3((BB * NN) / 256), dim3(256), 0, stream, AGG, CST, x, mask, out);
}